// Round 7
// baseline (1915.696 us; speedup 1.0000x reference)
//
#include <hip/hip_runtime.h>
#include <hip/hip_bf16.h>

typedef __attribute__((ext_vector_type(8)))  short short8v;
typedef __attribute__((ext_vector_type(16))) float f32x16;
typedef __attribute__((ext_vector_type(4)))  int   int4v;

// ===========================================================================
// Encoder, PX-coarsened (adjacent rows): conv3x3(CIN->36) + BN + LIF + mean.
// Block: TXX x TYY px tile, TXX*TYY/PX threads; each thread owns PX
// vertically ADJACENT pixels (overlapping windows: (PX+2) rows of LDS reads
// feed PX*9 FMAs per co). COCHUNK co per block (blockIdx.z).
// acc[COCHUNK][PX] kept <=24 to stay register-resident (R5 lesson).
// Writes avg channel-last [b][y][x][40] bf16.
// ===========================================================================
template<int CIN, int CICHUNK, int COCHUNK, int TXX, int TYY, int PX>
__global__ __launch_bounds__(TXX* TYY / PX) void enc_px(
    const float* __restrict__ feat,      // [16, CIN, H, W]
    const float* __restrict__ w,         // [36, CIN, 3, 3]
    const float* __restrict__ bn_s, const float* __restrict__ bn_b,
    const float* __restrict__ thr, const float* __restrict__ beta_raw,
    __hip_bfloat16* __restrict__ avg,    // [16][H][W][40]
    int H, int W, int tiles_x)
{
    const int TPB = TXX * TYY / PX;
    const int HR  = TYY + 2, HC = TXX + 2;
    __shared__ float fs[CICHUNK][HR][HC];

    const int tid = threadIdx.x;
    const int b   = blockIdx.y;
    const int co0 = blockIdx.z * COCHUNK;
    const int tx0 = (blockIdx.x % tiles_x) * TXX;
    const int ty0 = (blockIdx.x / tiles_x) * TYY;

    const int tx = tid % TXX;
    const int py = tid / TXX;           // 0..TYY/PX-1, owns rows py*PX..+PX-1

    float acc[COCHUNK][PX];
    #pragma unroll
    for (int j = 0; j < COCHUNK; ++j)
        #pragma unroll
        for (int p = 0; p < PX; ++p) acc[j][p] = 0.f;

    const float* fb = feat + (long)b * CIN * H * W;

    for (int cc = 0; cc < CIN; cc += CICHUNK) {
        for (int i = tid; i < CICHUNK * HR * HC; i += TPB) {
            int ci = i / (HR * HC);
            int r  = i % (HR * HC);
            int hy = r / HC, hx = r % HC;
            int gy = ty0 + hy - 1, gx = tx0 + hx - 1;
            float v = 0.f;
            if (gy >= 0 && gy < H && gx >= 0 && gx < W)
                v = fb[((long)(cc + ci) * H + gy) * W + gx];
            fs[ci][hy][hx] = v;
        }
        __syncthreads();

        for (int ci = 0; ci < CICHUNK; ++ci) {
            float f[PX + 2][3];
            #pragma unroll
            for (int r = 0; r < PX + 2; ++r) {
                f[r][0] = fs[ci][py * PX + r][tx];
                f[r][1] = fs[ci][py * PX + r][tx + 1];
                f[r][2] = fs[ci][py * PX + r][tx + 2];
            }
            const float* wq = w + (long)(cc + ci) * 9;
            #pragma unroll
            for (int j = 0; j < COCHUNK; ++j) {
                const float* ww = wq + (long)(co0 + j) * CIN * 9;  // uniform -> s_load
                #pragma unroll
                for (int p = 0; p < PX; ++p) {
                    acc[j][p] += f[p    ][0] * ww[0] + f[p    ][1] * ww[1] + f[p    ][2] * ww[2]
                               + f[p + 1][0] * ww[3] + f[p + 1][1] * ww[4] + f[p + 1][2] * ww[5]
                               + f[p + 2][0] * ww[6] + f[p + 2][1] * ww[7] + f[p + 2][2] * ww[8];
                }
            }
        }
        __syncthreads();
    }

    // Per-channel scalars (uniform).
    float sc[COCHUNK], sb[COCHUNK], bt[COCHUNK], th[COCHUNK];
    #pragma unroll
    for (int j = 0; j < COCHUNK; ++j) {
        int co = co0 + j;
        sc[j] = bn_s[co]; sb[j] = bn_b[co];
        bt[j] = 1.f / (1.f + expf(-beta_raw[co]));
        th[j] = thr[co];
    }

    #pragma unroll
    for (int p = 0; p < PX; ++p) {
        const int oy = ty0 + py * PX + p, ox = tx0 + tx;
        if (oy < H && ox < W) {
            float cnt[COCHUNK];
            #pragma unroll
            for (int j = 0; j < COCHUNK; ++j) {
                float h = acc[j][p] * sc[j] + sb[j];
                float m = 0.f, c2 = 0.f;
                #pragma unroll
                for (int s = 0; s < 4; ++s) {
                    m = bt[j] * m + h;
                    if (m > th[j]) { c2 += 1.f; m -= th[j]; }
                }
                cnt[j] = c2 * 0.25f;
            }
            unsigned* dp = (unsigned*)(avg + ((long)(b * H + oy) * W + ox) * 40 + co0);
            #pragma unroll
            for (int j2 = 0; j2 < COCHUNK / 2; ++j2) {
                __hip_bfloat16 h0 = __float2bfloat16(cnt[2 * j2]);
                __hip_bfloat16 h1 = __float2bfloat16(cnt[2 * j2 + 1]);
                unsigned u0 = *(unsigned short*)&h0;
                unsigned u1 = *(unsigned short*)&h1;
                dp[j2] = u0 | (u1 << 16);
            }
        }
    }
}

// ===========================================================================
// Original encoder (enc5 ci-split + fallback path).
// ===========================================================================
template<int CIN, int CIPER, int CICHUNK, int COCHUNK, int TDIM, bool PARTIAL, bool CL>
__global__ __launch_bounds__(TDIM* TDIM) void enc_tiled(
    const float* __restrict__ feat,
    const float* __restrict__ w,
    const float* __restrict__ bn_s, const float* __restrict__ bn_b,
    const float* __restrict__ thr, const float* __restrict__ beta_raw,
    __hip_bfloat16* __restrict__ avg,
    float* __restrict__ partial,
    int H, int W, int tiles_x)
{
    const int TPB  = TDIM * TDIM;
    const int HALOD = TDIM + 2;
    const int NCO  = 36 / COCHUNK;
    __shared__ float fs[CICHUNK][HALOD][HALOD];

    const int tile = blockIdx.x;
    const int b    = blockIdx.y;
    const int coc  = blockIdx.z % NCO;
    const int cis  = blockIdx.z / NCO;
    const int co0  = coc * COCHUNK;
    const int tx0  = (tile % tiles_x) * TDIM;
    const int ty0  = (tile / tiles_x) * TDIM;

    const int tx = threadIdx.x % TDIM;
    const int ty = threadIdx.x / TDIM;
    const int ox = tx0 + tx, oy = ty0 + ty;

    float acc[COCHUNK];
    #pragma unroll
    for (int c = 0; c < COCHUNK; ++c) acc[c] = 0.f;

    const float* fb = feat + (long)b * CIN * H * W;
    const int ci_base = cis * CIPER;

    for (int cc = ci_base; cc < ci_base + CIPER; cc += CICHUNK) {
        for (int i = threadIdx.x; i < CICHUNK * HALOD * HALOD; i += TPB) {
            int ci = i / (HALOD * HALOD);
            int r  = i % (HALOD * HALOD);
            int hy = r / HALOD, hx = r % HALOD;
            int gy = ty0 + hy - 1, gx = tx0 + hx - 1;
            float v = 0.f;
            if (gy >= 0 && gy < H && gx >= 0 && gx < W)
                v = fb[((long)(cc + ci) * H + gy) * W + gx];
            fs[ci][hy][hx] = v;
        }
        __syncthreads();

        for (int ci = 0; ci < CICHUNK; ++ci) {
            float f0 = fs[ci][ty    ][tx], f1 = fs[ci][ty    ][tx+1], f2 = fs[ci][ty    ][tx+2];
            float f3 = fs[ci][ty + 1][tx], f4 = fs[ci][ty + 1][tx+1], f5 = fs[ci][ty + 1][tx+2];
            float f6 = fs[ci][ty + 2][tx], f7 = fs[ci][ty + 2][tx+1], f8 = fs[ci][ty + 2][tx+2];
            const float* wq = w + (long)(cc + ci) * 9;
            #pragma unroll
            for (int j = 0; j < COCHUNK; ++j) {
                const float* ww = wq + (long)(co0 + j) * CIN * 9;  // uniform -> s_load
                acc[j] += f0 * ww[0] + f1 * ww[1] + f2 * ww[2]
                        + f3 * ww[3] + f4 * ww[4] + f5 * ww[5]
                        + f6 * ww[6] + f7 * ww[7] + f8 * ww[8];
            }
        }
        __syncthreads();
    }

    if (ox < W && oy < H) {
        if (PARTIAL) {
            #pragma unroll
            for (int j = 0; j < COCHUNK; ++j)
                partial[((((long)cis * 16 + b) * 36 + (co0 + j)) * H + oy) * W + ox] = acc[j];
        } else {
            float cnt[COCHUNK];
            #pragma unroll
            for (int j = 0; j < COCHUNK; ++j) {
                int co = co0 + j;
                float h    = acc[j] * bn_s[co] + bn_b[co];
                float beta = 1.f / (1.f + expf(-beta_raw[co]));
                float t    = thr[co];
                float m = 0.f, c2 = 0.f;
                #pragma unroll
                for (int s = 0; s < 4; ++s) {
                    m = beta * m + h;
                    if (m > t) { c2 += 1.f; m -= t; }
                }
                cnt[j] = c2 * 0.25f;
            }
            if (CL) {
                unsigned* dp = (unsigned*)(avg + ((long)(b * H + oy) * W + ox) * 40 + co0);
                #pragma unroll
                for (int j2 = 0; j2 < COCHUNK / 2; ++j2) {
                    __hip_bfloat16 h0 = __float2bfloat16(cnt[2 * j2]);
                    __hip_bfloat16 h1 = __float2bfloat16(cnt[2 * j2 + 1]);
                    unsigned u0 = *(unsigned short*)&h0;
                    unsigned u1 = *(unsigned short*)&h1;
                    dp[j2] = u0 | (u1 << 16);
                }
            } else {
                #pragma unroll
                for (int j = 0; j < COCHUNK; ++j)
                    avg[(((long)b * 36 + (co0 + j)) * H + oy) * W + ox] = __float2bfloat16(cnt[j]);
            }
        }
    }
}

// ===========================================================================
// Combine ci-split partials + BN + LIF + mean -> bf16 avg (CL or NCHW).
// ===========================================================================
template<int SPLITS, bool CL>
__global__ __launch_bounds__(256) void combine_lif(
    const float* __restrict__ partial,
    const float* __restrict__ bn_s, const float* __restrict__ bn_b,
    const float* __restrict__ thr, const float* __restrict__ beta_raw,
    __hip_bfloat16* __restrict__ avg, int H, int W, int total)
{
    int idx = blockIdx.x * 256 + threadIdx.x;
    if (idx >= total) return;
    int HW = H * W;
    int co = (idx / HW) % 36;
    float h = 0.f;
    #pragma unroll
    for (int s = 0; s < SPLITS; ++s) h += partial[(long)s * total + idx];
    h = h * bn_s[co] + bn_b[co];
    float beta = 1.f / (1.f + expf(-beta_raw[co]));
    float t    = thr[co];
    float m = 0.f, cnt = 0.f;
    #pragma unroll
    for (int s = 0; s < 4; ++s) {
        m = beta * m + h;
        if (m > t) { cnt += 1.f; m -= t; }
    }
    if (CL) {
        int b = idx / (36 * HW);
        int rem = idx % HW;
        int y = rem / W, x = rem % W;
        avg[((long)(b * H + y) * W + x) * 40 + co] = __float2bfloat16(cnt * 0.25f);
    } else {
        avg[idx] = __float2bfloat16(cnt * 0.25f);
    }
}

// ===========================================================================
// Weight prepack for MFMA decoder.
// ===========================================================================
__global__ __launch_bounds__(256) void pack_w(
    const float* __restrict__ w, __hip_bfloat16* __restrict__ ap, int total)
{
    int idx = blockIdx.x * 256 + threadIdx.x;   // one per (cg,s,h,m)
    if (idx >= total) return;
    int m  = idx & 31;
    int h  = (idx >> 5) & 1;
    int s  = (idx >> 6) % 23;
    int cg = idx / (23 * 64);
    int o  = 2 * s + h;
    int co = cg * 32 + m;
    unsigned short v[8];
    #pragma unroll
    for (int j = 0; j < 8; ++j) {
        float x = 0.f;
        if (o < 45) {
            int tap = o / 5, oct = o % 5, ci = oct * 8 + j;
            if (ci < 36) x = w[(long)co * 324 + ci * 9 + tap];
        }
        __hip_bfloat16 hv = __float2bfloat16(x);
        v[j] = *(unsigned short*)&hv;
    }
    *(int4v*)(ap + (long)idx * 8) = *(int4v*)v;
}

// ===========================================================================
// MFMA decoder: conv3x3(36->Cout) + BN + SiLU.
// ===========================================================================
template<int COG>
__global__ __launch_bounds__(256) void dec_mfma(
    const __hip_bfloat16* __restrict__ avg_cl,   // [B][H][W][40]
    const __hip_bfloat16* __restrict__ apack,
    const float* __restrict__ bn_s, const float* __restrict__ bn_b,
    float* __restrict__ out, int Cout, int H, int W, int tiles_x)
{
    __shared__ __hip_bfloat16 tile[12960];       // [18][18][40] = 25920 B

    const int tid    = threadIdx.x;
    const int b      = blockIdx.y;
    const int cgbase = blockIdx.z * COG;
    const int tx0 = (blockIdx.x % tiles_x) * 16;
    const int ty0 = (blockIdx.x / tiles_x) * 16;

    {   // stage halo tile (channel-last), zero-padded, b128 both sides
        const __hip_bfloat16* ab = avg_cl + (long)b * H * W * 40;
        for (int i = tid; i < 1620; i += 256) {
            int row = i / 90, u = i - row * 90;
            int px = u / 5, un = u - px * 5;
            int gy = ty0 + row - 1, gx = tx0 + px - 1;
            int4v v = {0, 0, 0, 0};
            if (gy >= 0 && gy < H && gx >= 0 && gx < W)
                v = *(const int4v*)(ab + ((long)gy * W + gx) * 40 + un * 8);
            *(int4v*)(tile + (row * 18 + px) * 40 + un * 8) = v;
        }
    }
    __syncthreads();

    const int lane = tid & 63;
    const int wv   = tid >> 6;
    const int h    = lane >> 5;
    const int n    = lane & 31;
    const int lx   = n & 15;
    const int ly0  = wv * 4 + (n >> 4);

    const char* tb  = (const char*)tile;
    const int   bb0 = ((ly0 + 1) * 18 + (lx + 1)) * 80;
    const int   bb1 = bb0 + 2 * 18 * 80;

    const char* ap = (const char*)apack + (long)cgbase * 23552 + h * 512 + n * 16;

    f32x16 acc[COG][2];
    #pragma unroll
    for (int cg = 0; cg < COG; ++cg)
        #pragma unroll
        for (int pf = 0; pf < 2; ++pf)
            #pragma unroll
            for (int k = 0; k < 16; ++k) acc[cg][pf][k] = 0.f;

    #pragma unroll
    for (int s = 0; s < 23; ++s) {
        int o0 = 2 * s;     if (o0 > 44) o0 = 44;
        int o1 = 2 * s + 1; if (o1 > 44) o1 = 44;
        const int C0 = ((o0 / 5) / 3 - 1) * 1440 + ((o0 / 5) % 3 - 1) * 80 + (o0 % 5) * 16;
        const int C1 = ((o1 / 5) / 3 - 1) * 1440 + ((o1 / 5) % 3 - 1) * 80 + (o1 % 5) * 16;
        const int offc = h ? C1 : C0;
        short8v bf0 = *(const short8v*)(tb + (bb0 + offc));
        short8v bf1 = *(const short8v*)(tb + (bb1 + offc));
        #pragma unroll
        for (int cg = 0; cg < COG; ++cg) {
            short8v af = *(const short8v*)(ap + cg * 23552 + s * 1024);
            acc[cg][0] = __builtin_amdgcn_mfma_f32_32x32x16_bf16(af, bf0, acc[cg][0], 0, 0, 0);
            acc[cg][1] = __builtin_amdgcn_mfma_f32_32x32x16_bf16(af, bf1, acc[cg][1], 0, 0, 0);
        }
    }

    #pragma unroll
    for (int cg = 0; cg < COG; ++cg) {
        #pragma unroll
        for (int r = 0; r < 16; ++r) {
            const int co = ((cgbase + cg) << 5) + (r & 3) + ((r >> 2) << 3) + (h << 2);
            const float sc = bn_s[co], bc = bn_b[co];
            #pragma unroll
            for (int pf = 0; pf < 2; ++pf) {
                const int ly = ly0 + pf * 2;
                const int gy = ty0 + ly, gx = tx0 + lx;
                float v = acc[cg][pf][r] * sc + bc;
                v = v / (1.f + __expf(-v));
                if (gy < H && gx < W)
                    out[(((long)b * Cout + co) * H + gy) * W + gx] = v;
            }
        }
    }
}

// ===========================================================================
// Fallback decoder (VALU, NCHW avg).
// ===========================================================================
template<int COCHUNK, int TDIM>
__global__ __launch_bounds__(TDIM* TDIM) void dec_tiled(
    const __hip_bfloat16* __restrict__ avg,
    const float* __restrict__ w,
    const float* __restrict__ bn_s, const float* __restrict__ bn_b,
    float* __restrict__ out,
    int Cout, int H, int W, int tiles_x)
{
    const int CIN = 36;
    const int TPB = TDIM * TDIM;
    const int HALOD = TDIM + 2;
    __shared__ float fs[CIN][HALOD][HALOD];

    const int tile = blockIdx.x;
    const int b    = blockIdx.y;
    const int co0  = blockIdx.z * COCHUNK;
    const int tx0  = (tile % tiles_x) * TDIM;
    const int ty0  = (tile / tiles_x) * TDIM;

    const int tx = threadIdx.x % TDIM;
    const int ty = threadIdx.x / TDIM;
    const int ox = tx0 + tx, oy = ty0 + ty;

    const __hip_bfloat16* ab = avg + (long)b * CIN * H * W;

    for (int i = threadIdx.x; i < CIN * HALOD * HALOD; i += TPB) {
        int ci = i / (HALOD * HALOD);
        int r  = i % (HALOD * HALOD);
        int hy = r / HALOD, hx = r % HALOD;
        int gy = ty0 + hy - 1, gx = tx0 + hx - 1;
        float v = 0.f;
        if (gy >= 0 && gy < H && gx >= 0 && gx < W)
            v = __bfloat162float(ab[((long)ci * H + gy) * W + gx]);
        fs[ci][hy][hx] = v;
    }
    __syncthreads();

    float acc[COCHUNK];
    #pragma unroll
    for (int j = 0; j < COCHUNK; ++j) acc[j] = 0.f;

    for (int ci = 0; ci < CIN; ++ci) {
        float f0 = fs[ci][ty    ][tx], f1 = fs[ci][ty    ][tx+1], f2 = fs[ci][ty    ][tx+2];
        float f3 = fs[ci][ty + 1][tx], f4 = fs[ci][ty + 1][tx+1], f5 = fs[ci][ty + 1][tx+2];
        float f6 = fs[ci][ty + 2][tx], f7 = fs[ci][ty + 2][tx+1], f8 = fs[ci][ty + 2][tx+2];
        #pragma unroll
        for (int j = 0; j < COCHUNK; ++j) {
            const float* ww = w + ((long)(co0 + j) * CIN + ci) * 9;
            acc[j] += f0 * ww[0] + f1 * ww[1] + f2 * ww[2]
                    + f3 * ww[3] + f4 * ww[4] + f5 * ww[5]
                    + f6 * ww[6] + f7 * ww[7] + f8 * ww[8];
        }
    }

    if (ox < W && oy < H) {
        #pragma unroll
        for (int j = 0; j < COCHUNK; ++j) {
            int co = co0 + j;
            float v = acc[j] * bn_s[co] + bn_b[co];
            out[(((long)b * Cout + co) * H + oy) * W + ox] = v / (1.f + expf(-v));
        }
    }
}

// ===========================================================================
extern "C" void kernel_launch(void* const* d_in, const int* in_sizes, int n_in,
                              void* d_out, int out_size, void* d_ws, size_t ws_size,
                              hipStream_t stream)
{
    const int B = 16;
    const int C[3] = {64, 128, 256};
    const int S[3] = {160, 80, 40};

    float* out = (float*)d_out;
    long out_off[3]; long off = 0;
    for (int l = 0; l < 3; ++l) { out_off[l] = off; off += (long)B * C[l] * S[l] * S[l]; }

    // ---- new-path workspace layout (bytes) ----
    const long avgcl_bytes[3] = {32768000L, 8192000L, 2048000L};   // B*H*W*40*2
    long avgcl_off[3]; long boff = 0;
    for (int l = 0; l < 3; ++l) { avgcl_off[l] = boff; boff += avgcl_bytes[l]; }
    const long avgcl_total = boff;
    const long ap_bytes[3] = {47104L, 94208L, 188416L};             // (C/32)*23552
    long ap_off[3];
    for (int l = 0; l < 3; ++l) { ap_off[l] = boff; boff += ap_bytes[l]; }
    const long part5_off = boff;
    const long part5_bytes = 4L * B * 36 * 1600 * 4;
    const size_t need_full = (size_t)(part5_off + part5_bytes);
    const size_t need_min  = (size_t)part5_off;

    char* wsb = (char*)d_ws;

    if (ws_size >= need_min) {
        // ================= NEW PATH =================
        const bool split5 = ws_size >= need_full;
        hipMemsetAsync(wsb, 0, avgcl_total, stream);   // zero avg_cl incl. ci-pad

        for (int l = 0; l < 3; ++l) {
            const float* dec_w = (const float*)d_in[9 * l + 6];
            int total = (C[l] / 32) * 23 * 2 * 32;
            pack_w<<<(total + 255) / 256, 256, 0, stream>>>(
                dec_w, (__hip_bfloat16*)(wsb + ap_off[l]), total);
        }

        for (int l = 0; l < 3; ++l) {
            const int base = 9 * l;
            const float* feat     = (const float*)d_in[base + 0];
            const float* enc_w    = (const float*)d_in[base + 1];
            const float* enc_bn_s = (const float*)d_in[base + 2];
            const float* enc_bn_b = (const float*)d_in[base + 3];
            const float* enc_thr  = (const float*)d_in[base + 4];
            const float* enc_beta = (const float*)d_in[base + 5];
            const float* dec_bn_s = (const float*)d_in[base + 7];
            const float* dec_bn_b = (const float*)d_in[base + 8];

            const int Hs = S[l], Wsz = S[l];
            __hip_bfloat16* avg_cl = (__hip_bfloat16*)(wsb + avgcl_off[l]);
            const __hip_bfloat16* ap = (const __hip_bfloat16*)(wsb + ap_off[l]);
            float* r = out + out_off[l];

            if (l == 0) {
                // 160x160: 5x10 tiles of 32x16, 256 thr, 2 px/thread, co-split x3
                dim3 eg(50, B, 3);
                enc_px<64, 8, 12, 32, 16, 2><<<eg, 256, 0, stream>>>(
                    feat, enc_w, enc_bn_s, enc_bn_b, enc_thr, enc_beta, avg_cl, Hs, Wsz, 5);
                dim3 dg(100, B, 1);
                dec_mfma<2><<<dg, 256, 0, stream>>>(avg_cl, ap, dec_bn_s, dec_bn_b, r, 64, Hs, Wsz, 10);
            } else if (l == 1) {
                // 80x80: 1x10 tiles of 80x8, 320 thr, 2 px/thread, co-split x6
                dim3 eg(10, B, 6);
                enc_px<128, 8, 6, 80, 8, 2><<<eg, 320, 0, stream>>>(
                    feat, enc_w, enc_bn_s, enc_bn_b, enc_thr, enc_beta, avg_cl, Hs, Wsz, 1);
                dim3 dg(25, B, 1);
                dec_mfma<4><<<dg, 256, 0, stream>>>(avg_cl, ap, dec_bn_s, dec_bn_b, r, 128, Hs, Wsz, 5);
            } else {
                if (split5) {
                    float* partial5 = (float*)(wsb + part5_off);
                    dim3 eg(25, B, 12);   // 4 ci-splits x 3 co-chunks
                    enc_tiled<256, 64, 16, 12, 8, true, true><<<eg, 64, 0, stream>>>(
                        feat, enc_w, enc_bn_s, enc_bn_b, enc_thr, enc_beta, nullptr, partial5, Hs, Wsz, 5);
                    int total = B * 36 * Hs * Wsz;
                    combine_lif<4, true><<<(total + 255) / 256, 256, 0, stream>>>(
                        partial5, enc_bn_s, enc_bn_b, enc_thr, enc_beta, avg_cl, Hs, Wsz, total);
                } else {
                    dim3 eg(25, B, 3);
                    enc_tiled<256, 256, 16, 12, 8, false, true><<<eg, 64, 0, stream>>>(
                        feat, enc_w, enc_bn_s, enc_bn_b, enc_thr, enc_beta, avg_cl, nullptr, Hs, Wsz, 5);
                }
                dim3 dg(9, B, 2);
                dec_mfma<4><<<dg, 256, 0, stream>>>(avg_cl, ap, dec_bn_s, dec_bn_b, r, 256, Hs, Wsz, 3);
            }
        }
    } else {
        // ================= FALLBACK (NCHW, VALU decoder) =================
        __hip_bfloat16* ws = (__hip_bfloat16*)d_ws;
        long avg_off2[3]; long eoff = 0;
        for (int l = 0; l < 3; ++l) { avg_off2[l] = eoff; eoff += (long)B * 36 * S[l] * S[l]; }
        float* partial5 = (float*)(ws + ((eoff + 7) & ~7L));
        const long part5f = 4L * B * 36 * 40 * 40;
        const size_t old_need = (size_t)((eoff + 7) & ~7L) * 2 + part5f * 4;
        const bool split5 = ws_size >= old_need;

        for (int l = 0; l < 3; ++l) {
            const int base = 9 * l;
            const float* feat     = (const float*)d_in[base + 0];
            const float* enc_w    = (const float*)d_in[base + 1];
            const float* enc_bn_s = (const float*)d_in[base + 2];
            const float* enc_bn_b = (const float*)d_in[base + 3];
            const float* enc_thr  = (const float*)d_in[base + 4];
            const float* enc_beta = (const float*)d_in[base + 5];
            const float* dec_w    = (const float*)d_in[base + 6];
            const float* dec_bn_s = (const float*)d_in[base + 7];
            const float* dec_bn_b = (const float*)d_in[base + 8];

            const int Hs = S[l], Wsz = S[l], Cl = C[l];
            __hip_bfloat16* avg = ws + avg_off2[l];
            float* r = out + out_off[l];

            if (l == 0) {
                dim3 eg(100, B, 3);
                enc_tiled<64, 64, 16, 12, 16, false, false><<<eg, 256, 0, stream>>>(
                    feat, enc_w, enc_bn_s, enc_bn_b, enc_thr, enc_beta, avg, nullptr, Hs, Wsz, 10);
                dim3 dg(100, B, 2);
                dec_tiled<32, 16><<<dg, 256, 0, stream>>>(avg, dec_w, dec_bn_s, dec_bn_b, r, Cl, Hs, Wsz, 10);
            } else if (l == 1) {
                dim3 eg(25, B, 3);
                enc_tiled<128, 128, 16, 12, 16, false, false><<<eg, 256, 0, stream>>>(
                    feat, enc_w, enc_bn_s, enc_bn_b, enc_thr, enc_beta, avg, nullptr, Hs, Wsz, 5);
                dim3 dg(25, B, 4);
                dec_tiled<32, 16><<<dg, 256, 0, stream>>>(avg, dec_w, dec_bn_s, dec_bn_b, r, Cl, Hs, Wsz, 5);
            } else {
                if (split5) {
                    dim3 eg(25, B, 12);
                    enc_tiled<256, 64, 16, 12, 8, true, false><<<eg, 64, 0, stream>>>(
                        feat, enc_w, enc_bn_s, enc_bn_b, enc_thr, enc_beta, nullptr, partial5, Hs, Wsz, 5);
                    int total = B * 36 * Hs * Wsz;
                    combine_lif<4, false><<<(total + 255) / 256, 256, 0, stream>>>(
                        partial5, enc_bn_s, enc_bn_b, enc_thr, enc_beta, avg, Hs, Wsz, total);
                } else {
                    dim3 eg(25, B, 3);
                    enc_tiled<256, 256, 16, 12, 8, false, false><<<eg, 64, 0, stream>>>(
                        feat, enc_w, enc_bn_s, enc_bn_b, enc_thr, enc_beta, avg, nullptr, Hs, Wsz, 5);
                }
                dim3 dg(25, B, 16);
                dec_tiled<16, 8><<<dg, 64, 0, stream>>>(avg, dec_w, dec_bn_s, dec_bn_b, r, Cl, Hs, Wsz, 5);
            }
        }
    }
}

// Round 8
// 977.168 us; speedup vs baseline: 1.9605x; 1.9605x over previous
//
#include <hip/hip_runtime.h>
#include <hip/hip_bf16.h>

typedef __attribute__((ext_vector_type(8)))  short short8v;
typedef __attribute__((ext_vector_type(16))) float f32x16;
typedef __attribute__((ext_vector_type(4)))  int   int4v;

// ===========================================================================
// Encoder, PX-coarsened (adjacent rows): conv3x3(CIN->36) + BN + LIF + mean.
// PROVEN SHAPE RULES (R5-R7 lessons): TPB must be 256 (4 waves), TXX pow2,
// acc[COCHUNK][PX] <= 24. Violating any of these collapses VGPR/occupancy.
// ===========================================================================
template<int CIN, int CICHUNK, int COCHUNK, int TXX, int TYY, int PX>
__global__ __launch_bounds__(TXX* TYY / PX) void enc_px(
    const float* __restrict__ feat,      // [16, CIN, H, W]
    const float* __restrict__ w,         // [36, CIN, 3, 3]
    const float* __restrict__ bn_s, const float* __restrict__ bn_b,
    const float* __restrict__ thr, const float* __restrict__ beta_raw,
    __hip_bfloat16* __restrict__ avg,    // [16][H][W][40]
    int H, int W, int tiles_x)
{
    const int TPB = TXX * TYY / PX;
    const int HR  = TYY + 2, HC = TXX + 2;
    __shared__ float fs[CICHUNK][HR][HC];

    const int tid = threadIdx.x;
    const int b   = blockIdx.y;
    const int co0 = blockIdx.z * COCHUNK;
    const int tx0 = (blockIdx.x % tiles_x) * TXX;
    const int ty0 = (blockIdx.x / tiles_x) * TYY;

    const int tx = tid % TXX;
    const int py = tid / TXX;           // owns rows py*PX..py*PX+PX-1

    float acc[COCHUNK][PX];
    #pragma unroll
    for (int j = 0; j < COCHUNK; ++j)
        #pragma unroll
        for (int p = 0; p < PX; ++p) acc[j][p] = 0.f;

    const float* fb = feat + (long)b * CIN * H * W;

    for (int cc = 0; cc < CIN; cc += CICHUNK) {
        for (int i = tid; i < CICHUNK * HR * HC; i += TPB) {
            int ci = i / (HR * HC);
            int r  = i % (HR * HC);
            int hy = r / HC, hx = r % HC;
            int gy = ty0 + hy - 1, gx = tx0 + hx - 1;
            float v = 0.f;
            if (gy >= 0 && gy < H && gx >= 0 && gx < W)
                v = fb[((long)(cc + ci) * H + gy) * W + gx];
            fs[ci][hy][hx] = v;
        }
        __syncthreads();

        for (int ci = 0; ci < CICHUNK; ++ci) {
            float f[PX + 2][3];
            #pragma unroll
            for (int r = 0; r < PX + 2; ++r) {
                f[r][0] = fs[ci][py * PX + r][tx];
                f[r][1] = fs[ci][py * PX + r][tx + 1];
                f[r][2] = fs[ci][py * PX + r][tx + 2];
            }
            const float* wq = w + (long)(cc + ci) * 9;
            #pragma unroll
            for (int j = 0; j < COCHUNK; ++j) {
                const float* ww = wq + (long)(co0 + j) * CIN * 9;  // uniform -> s_load
                #pragma unroll
                for (int p = 0; p < PX; ++p) {
                    acc[j][p] += f[p    ][0] * ww[0] + f[p    ][1] * ww[1] + f[p    ][2] * ww[2]
                               + f[p + 1][0] * ww[3] + f[p + 1][1] * ww[4] + f[p + 1][2] * ww[5]
                               + f[p + 2][0] * ww[6] + f[p + 2][1] * ww[7] + f[p + 2][2] * ww[8];
                }
            }
        }
        __syncthreads();
    }

    // Per-channel scalars (uniform).
    float sc[COCHUNK], sb[COCHUNK], bt[COCHUNK], th[COCHUNK];
    #pragma unroll
    for (int j = 0; j < COCHUNK; ++j) {
        int co = co0 + j;
        sc[j] = bn_s[co]; sb[j] = bn_b[co];
        bt[j] = 1.f / (1.f + expf(-beta_raw[co]));
        th[j] = thr[co];
    }

    #pragma unroll
    for (int p = 0; p < PX; ++p) {
        const int oy = ty0 + py * PX + p, ox = tx0 + tx;
        if (oy < H && ox < W) {
            float cnt[COCHUNK];
            #pragma unroll
            for (int j = 0; j < COCHUNK; ++j) {
                float h = acc[j][p] * sc[j] + sb[j];
                float m = 0.f, c2 = 0.f;
                #pragma unroll
                for (int s = 0; s < 4; ++s) {
                    m = bt[j] * m + h;
                    if (m > th[j]) { c2 += 1.f; m -= th[j]; }
                }
                cnt[j] = c2 * 0.25f;
            }
            unsigned* dp = (unsigned*)(avg + ((long)(b * H + oy) * W + ox) * 40 + co0);
            #pragma unroll
            for (int j2 = 0; j2 < COCHUNK / 2; ++j2) {
                __hip_bfloat16 h0 = __float2bfloat16(cnt[2 * j2]);
                __hip_bfloat16 h1 = __float2bfloat16(cnt[2 * j2 + 1]);
                unsigned u0 = *(unsigned short*)&h0;
                unsigned u1 = *(unsigned short*)&h1;
                dp[j2] = u0 | (u1 << 16);
            }
        }
    }
}

// ===========================================================================
// Original encoder (enc5 ci-split + fallback path).
// ===========================================================================
template<int CIN, int CIPER, int CICHUNK, int COCHUNK, int TDIM, bool PARTIAL, bool CL>
__global__ __launch_bounds__(TDIM* TDIM) void enc_tiled(
    const float* __restrict__ feat,
    const float* __restrict__ w,
    const float* __restrict__ bn_s, const float* __restrict__ bn_b,
    const float* __restrict__ thr, const float* __restrict__ beta_raw,
    __hip_bfloat16* __restrict__ avg,
    float* __restrict__ partial,
    int H, int W, int tiles_x)
{
    const int TPB  = TDIM * TDIM;
    const int HALOD = TDIM + 2;
    const int NCO  = 36 / COCHUNK;
    __shared__ float fs[CICHUNK][HALOD][HALOD];

    const int tile = blockIdx.x;
    const int b    = blockIdx.y;
    const int coc  = blockIdx.z % NCO;
    const int cis  = blockIdx.z / NCO;
    const int co0  = coc * COCHUNK;
    const int tx0  = (tile % tiles_x) * TDIM;
    const int ty0  = (tile / tiles_x) * TDIM;

    const int tx = threadIdx.x % TDIM;
    const int ty = threadIdx.x / TDIM;
    const int ox = tx0 + tx, oy = ty0 + ty;

    float acc[COCHUNK];
    #pragma unroll
    for (int c = 0; c < COCHUNK; ++c) acc[c] = 0.f;

    const float* fb = feat + (long)b * CIN * H * W;
    const int ci_base = cis * CIPER;

    for (int cc = ci_base; cc < ci_base + CIPER; cc += CICHUNK) {
        for (int i = threadIdx.x; i < CICHUNK * HALOD * HALOD; i += TPB) {
            int ci = i / (HALOD * HALOD);
            int r  = i % (HALOD * HALOD);
            int hy = r / HALOD, hx = r % HALOD;
            int gy = ty0 + hy - 1, gx = tx0 + hx - 1;
            float v = 0.f;
            if (gy >= 0 && gy < H && gx >= 0 && gx < W)
                v = fb[((long)(cc + ci) * H + gy) * W + gx];
            fs[ci][hy][hx] = v;
        }
        __syncthreads();

        for (int ci = 0; ci < CICHUNK; ++ci) {
            float f0 = fs[ci][ty    ][tx], f1 = fs[ci][ty    ][tx+1], f2 = fs[ci][ty    ][tx+2];
            float f3 = fs[ci][ty + 1][tx], f4 = fs[ci][ty + 1][tx+1], f5 = fs[ci][ty + 1][tx+2];
            float f6 = fs[ci][ty + 2][tx], f7 = fs[ci][ty + 2][tx+1], f8 = fs[ci][ty + 2][tx+2];
            const float* wq = w + (long)(cc + ci) * 9;
            #pragma unroll
            for (int j = 0; j < COCHUNK; ++j) {
                const float* ww = wq + (long)(co0 + j) * CIN * 9;  // uniform -> s_load
                acc[j] += f0 * ww[0] + f1 * ww[1] + f2 * ww[2]
                        + f3 * ww[3] + f4 * ww[4] + f5 * ww[5]
                        + f6 * ww[6] + f7 * ww[7] + f8 * ww[8];
            }
        }
        __syncthreads();
    }

    if (ox < W && oy < H) {
        if (PARTIAL) {
            #pragma unroll
            for (int j = 0; j < COCHUNK; ++j)
                partial[((((long)cis * 16 + b) * 36 + (co0 + j)) * H + oy) * W + ox] = acc[j];
        } else {
            float cnt[COCHUNK];
            #pragma unroll
            for (int j = 0; j < COCHUNK; ++j) {
                int co = co0 + j;
                float h    = acc[j] * bn_s[co] + bn_b[co];
                float beta = 1.f / (1.f + expf(-beta_raw[co]));
                float t    = thr[co];
                float m = 0.f, c2 = 0.f;
                #pragma unroll
                for (int s = 0; s < 4; ++s) {
                    m = beta * m + h;
                    if (m > t) { c2 += 1.f; m -= t; }
                }
                cnt[j] = c2 * 0.25f;
            }
            if (CL) {
                unsigned* dp = (unsigned*)(avg + ((long)(b * H + oy) * W + ox) * 40 + co0);
                #pragma unroll
                for (int j2 = 0; j2 < COCHUNK / 2; ++j2) {
                    __hip_bfloat16 h0 = __float2bfloat16(cnt[2 * j2]);
                    __hip_bfloat16 h1 = __float2bfloat16(cnt[2 * j2 + 1]);
                    unsigned u0 = *(unsigned short*)&h0;
                    unsigned u1 = *(unsigned short*)&h1;
                    dp[j2] = u0 | (u1 << 16);
                }
            } else {
                #pragma unroll
                for (int j = 0; j < COCHUNK; ++j)
                    avg[(((long)b * 36 + (co0 + j)) * H + oy) * W + ox] = __float2bfloat16(cnt[j]);
            }
        }
    }
}

// ===========================================================================
// Combine ci-split partials + BN + LIF + mean -> bf16 avg (CL or NCHW).
// ===========================================================================
template<int SPLITS, bool CL>
__global__ __launch_bounds__(256) void combine_lif(
    const float* __restrict__ partial,
    const float* __restrict__ bn_s, const float* __restrict__ bn_b,
    const float* __restrict__ thr, const float* __restrict__ beta_raw,
    __hip_bfloat16* __restrict__ avg, int H, int W, int total)
{
    int idx = blockIdx.x * 256 + threadIdx.x;
    if (idx >= total) return;
    int HW = H * W;
    int co = (idx / HW) % 36;
    float h = 0.f;
    #pragma unroll
    for (int s = 0; s < SPLITS; ++s) h += partial[(long)s * total + idx];
    h = h * bn_s[co] + bn_b[co];
    float beta = 1.f / (1.f + expf(-beta_raw[co]));
    float t    = thr[co];
    float m = 0.f, cnt = 0.f;
    #pragma unroll
    for (int s = 0; s < 4; ++s) {
        m = beta * m + h;
        if (m > t) { cnt += 1.f; m -= t; }
    }
    if (CL) {
        int b = idx / (36 * HW);
        int rem = idx % HW;
        int y = rem / W, x = rem % W;
        avg[((long)(b * H + y) * W + x) * 40 + co] = __float2bfloat16(cnt * 0.25f);
    } else {
        avg[idx] = __float2bfloat16(cnt * 0.25f);
    }
}

// ===========================================================================
// Weight prepack for MFMA decoder.
// ===========================================================================
__global__ __launch_bounds__(256) void pack_w(
    const float* __restrict__ w, __hip_bfloat16* __restrict__ ap, int total)
{
    int idx = blockIdx.x * 256 + threadIdx.x;   // one per (cg,s,h,m)
    if (idx >= total) return;
    int m  = idx & 31;
    int h  = (idx >> 5) & 1;
    int s  = (idx >> 6) % 23;
    int cg = idx / (23 * 64);
    int o  = 2 * s + h;
    int co = cg * 32 + m;
    unsigned short v[8];
    #pragma unroll
    for (int j = 0; j < 8; ++j) {
        float x = 0.f;
        if (o < 45) {
            int tap = o / 5, oct = o % 5, ci = oct * 8 + j;
            if (ci < 36) x = w[(long)co * 324 + ci * 9 + tap];
        }
        __hip_bfloat16 hv = __float2bfloat16(x);
        v[j] = *(unsigned short*)&hv;
    }
    *(int4v*)(ap + (long)idx * 8) = *(int4v*)v;
}

// ===========================================================================
// MFMA decoder: conv3x3(36->Cout) + BN + SiLU.
// ===========================================================================
template<int COG>
__global__ __launch_bounds__(256) void dec_mfma(
    const __hip_bfloat16* __restrict__ avg_cl,   // [B][H][W][40]
    const __hip_bfloat16* __restrict__ apack,
    const float* __restrict__ bn_s, const float* __restrict__ bn_b,
    float* __restrict__ out, int Cout, int H, int W, int tiles_x)
{
    __shared__ __hip_bfloat16 tile[12960];       // [18][18][40] = 25920 B

    const int tid    = threadIdx.x;
    const int b      = blockIdx.y;
    const int cgbase = blockIdx.z * COG;
    const int tx0 = (blockIdx.x % tiles_x) * 16;
    const int ty0 = (blockIdx.x / tiles_x) * 16;

    {   // stage halo tile (channel-last), zero-padded, b128 both sides
        const __hip_bfloat16* ab = avg_cl + (long)b * H * W * 40;
        for (int i = tid; i < 1620; i += 256) {
            int row = i / 90, u = i - row * 90;
            int px = u / 5, un = u - px * 5;
            int gy = ty0 + row - 1, gx = tx0 + px - 1;
            int4v v = {0, 0, 0, 0};
            if (gy >= 0 && gy < H && gx >= 0 && gx < W)
                v = *(const int4v*)(ab + ((long)gy * W + gx) * 40 + un * 8);
            *(int4v*)(tile + (row * 18 + px) * 40 + un * 8) = v;
        }
    }
    __syncthreads();

    const int lane = tid & 63;
    const int wv   = tid >> 6;
    const int h    = lane >> 5;
    const int n    = lane & 31;
    const int lx   = n & 15;
    const int ly0  = wv * 4 + (n >> 4);

    const char* tb  = (const char*)tile;
    const int   bb0 = ((ly0 + 1) * 18 + (lx + 1)) * 80;
    const int   bb1 = bb0 + 2 * 18 * 80;

    const char* ap = (const char*)apack + (long)cgbase * 23552 + h * 512 + n * 16;

    f32x16 acc[COG][2];
    #pragma unroll
    for (int cg = 0; cg < COG; ++cg)
        #pragma unroll
        for (int pf = 0; pf < 2; ++pf)
            #pragma unroll
            for (int k = 0; k < 16; ++k) acc[cg][pf][k] = 0.f;

    #pragma unroll
    for (int s = 0; s < 23; ++s) {
        int o0 = 2 * s;     if (o0 > 44) o0 = 44;
        int o1 = 2 * s + 1; if (o1 > 44) o1 = 44;
        const int C0 = ((o0 / 5) / 3 - 1) * 1440 + ((o0 / 5) % 3 - 1) * 80 + (o0 % 5) * 16;
        const int C1 = ((o1 / 5) / 3 - 1) * 1440 + ((o1 / 5) % 3 - 1) * 80 + (o1 % 5) * 16;
        const int offc = h ? C1 : C0;
        short8v bf0 = *(const short8v*)(tb + (bb0 + offc));
        short8v bf1 = *(const short8v*)(tb + (bb1 + offc));
        #pragma unroll
        for (int cg = 0; cg < COG; ++cg) {
            short8v af = *(const short8v*)(ap + cg * 23552 + s * 1024);
            acc[cg][0] = __builtin_amdgcn_mfma_f32_32x32x16_bf16(af, bf0, acc[cg][0], 0, 0, 0);
            acc[cg][1] = __builtin_amdgcn_mfma_f32_32x32x16_bf16(af, bf1, acc[cg][1], 0, 0, 0);
        }
    }

    #pragma unroll
    for (int cg = 0; cg < COG; ++cg) {
        #pragma unroll
        for (int r = 0; r < 16; ++r) {
            const int co = ((cgbase + cg) << 5) + (r & 3) + ((r >> 2) << 3) + (h << 2);
            const float sc = bn_s[co], bc = bn_b[co];
            #pragma unroll
            for (int pf = 0; pf < 2; ++pf) {
                const int ly = ly0 + pf * 2;
                const int gy = ty0 + ly, gx = tx0 + lx;
                float v = acc[cg][pf][r] * sc + bc;
                v = v / (1.f + __expf(-v));
                if (gy < H && gx < W)
                    out[(((long)b * Cout + co) * H + gy) * W + gx] = v;
            }
        }
    }
}

// ===========================================================================
// Fallback decoder (VALU, NCHW avg).
// ===========================================================================
template<int COCHUNK, int TDIM>
__global__ __launch_bounds__(TDIM* TDIM) void dec_tiled(
    const __hip_bfloat16* __restrict__ avg,
    const float* __restrict__ w,
    const float* __restrict__ bn_s, const float* __restrict__ bn_b,
    float* __restrict__ out,
    int Cout, int H, int W, int tiles_x)
{
    const int CIN = 36;
    const int TPB = TDIM * TDIM;
    const int HALOD = TDIM + 2;
    __shared__ float fs[CIN][HALOD][HALOD];

    const int tile = blockIdx.x;
    const int b    = blockIdx.y;
    const int co0  = blockIdx.z * COCHUNK;
    const int tx0  = (tile % tiles_x) * TDIM;
    const int ty0  = (tile / tiles_x) * TDIM;

    const int tx = threadIdx.x % TDIM;
    const int ty = threadIdx.x / TDIM;
    const int ox = tx0 + tx, oy = ty0 + ty;

    const __hip_bfloat16* ab = avg + (long)b * CIN * H * W;

    for (int i = threadIdx.x; i < CIN * HALOD * HALOD; i += TPB) {
        int ci = i / (HALOD * HALOD);
        int r  = i % (HALOD * HALOD);
        int hy = r / HALOD, hx = r % HALOD;
        int gy = ty0 + hy - 1, gx = tx0 + hx - 1;
        float v = 0.f;
        if (gy >= 0 && gy < H && gx >= 0 && gx < W)
            v = __bfloat162float(ab[((long)ci * H + gy) * W + gx]);
        fs[ci][hy][hx] = v;
    }
    __syncthreads();

    float acc[COCHUNK];
    #pragma unroll
    for (int j = 0; j < COCHUNK; ++j) acc[j] = 0.f;

    for (int ci = 0; ci < CIN; ++ci) {
        float f0 = fs[ci][ty    ][tx], f1 = fs[ci][ty    ][tx+1], f2 = fs[ci][ty    ][tx+2];
        float f3 = fs[ci][ty + 1][tx], f4 = fs[ci][ty + 1][tx+1], f5 = fs[ci][ty + 1][tx+2];
        float f6 = fs[ci][ty + 2][tx], f7 = fs[ci][ty + 2][tx+1], f8 = fs[ci][ty + 2][tx+2];
        #pragma unroll
        for (int j = 0; j < COCHUNK; ++j) {
            const float* ww = w + ((long)(co0 + j) * CIN + ci) * 9;
            acc[j] += f0 * ww[0] + f1 * ww[1] + f2 * ww[2]
                    + f3 * ww[3] + f4 * ww[4] + f5 * ww[5]
                    + f6 * ww[6] + f7 * ww[7] + f8 * ww[8];
        }
    }

    if (ox < W && oy < H) {
        #pragma unroll
        for (int j = 0; j < COCHUNK; ++j) {
            int co = co0 + j;
            float v = acc[j] * bn_s[co] + bn_b[co];
            out[(((long)b * Cout + co) * H + oy) * W + ox] = v / (1.f + expf(-v));
        }
    }
}

// ===========================================================================
extern "C" void kernel_launch(void* const* d_in, const int* in_sizes, int n_in,
                              void* d_out, int out_size, void* d_ws, size_t ws_size,
                              hipStream_t stream)
{
    const int B = 16;
    const int C[3] = {64, 128, 256};
    const int S[3] = {160, 80, 40};

    float* out = (float*)d_out;
    long out_off[3]; long off = 0;
    for (int l = 0; l < 3; ++l) { out_off[l] = off; off += (long)B * C[l] * S[l] * S[l]; }

    // ---- new-path workspace layout (bytes) ----
    const long avgcl_bytes[3] = {32768000L, 8192000L, 2048000L};   // B*H*W*40*2
    long avgcl_off[3]; long boff = 0;
    for (int l = 0; l < 3; ++l) { avgcl_off[l] = boff; boff += avgcl_bytes[l]; }
    const long avgcl_total = boff;
    const long ap_bytes[3] = {47104L, 94208L, 188416L};             // (C/32)*23552
    long ap_off[3];
    for (int l = 0; l < 3; ++l) { ap_off[l] = boff; boff += ap_bytes[l]; }
    const long part5_off = boff;
    const long part5_bytes = 4L * B * 36 * 1600 * 4;
    const size_t need_full = (size_t)(part5_off + part5_bytes);
    const size_t need_min  = (size_t)part5_off;

    char* wsb = (char*)d_ws;

    if (ws_size >= need_min) {
        // ================= NEW PATH =================
        const bool split5 = ws_size >= need_full;
        hipMemsetAsync(wsb, 0, avgcl_total, stream);   // zero avg_cl incl. ci-pad

        for (int l = 0; l < 3; ++l) {
            const float* dec_w = (const float*)d_in[9 * l + 6];
            int total = (C[l] / 32) * 23 * 2 * 32;
            pack_w<<<(total + 255) / 256, 256, 0, stream>>>(
                dec_w, (__hip_bfloat16*)(wsb + ap_off[l]), total);
        }

        for (int l = 0; l < 3; ++l) {
            const int base = 9 * l;
            const float* feat     = (const float*)d_in[base + 0];
            const float* enc_w    = (const float*)d_in[base + 1];
            const float* enc_bn_s = (const float*)d_in[base + 2];
            const float* enc_bn_b = (const float*)d_in[base + 3];
            const float* enc_thr  = (const float*)d_in[base + 4];
            const float* enc_beta = (const float*)d_in[base + 5];
            const float* dec_bn_s = (const float*)d_in[base + 7];
            const float* dec_bn_b = (const float*)d_in[base + 8];

            const int Hs = S[l], Wsz = S[l];
            __hip_bfloat16* avg_cl = (__hip_bfloat16*)(wsb + avgcl_off[l]);
            const __hip_bfloat16* ap = (const __hip_bfloat16*)(wsb + ap_off[l]);
            float* r = out + out_off[l];

            if (l == 0) {
                // 160x160: 5x10 tiles of 32x16, 256 thr, 2 px/thread, co-split x3
                dim3 eg(50, B, 3);
                enc_px<64, 8, 12, 32, 16, 2><<<eg, 256, 0, stream>>>(
                    feat, enc_w, enc_bn_s, enc_bn_b, enc_thr, enc_beta, avg_cl, Hs, Wsz, 5);
                dim3 dg(100, B, 1);
                dec_mfma<2><<<dg, 256, 0, stream>>>(avg_cl, ap, dec_bn_s, dec_bn_b, r, 64, Hs, Wsz, 10);
            } else if (l == 1) {
                // 80x80: 5x3 tiles of 16x32 (last row masked), 256 thr, 2 px/thread,
                // co-split x3. Same proven enc_px shape as enc3, transposed tile.
                dim3 eg(15, B, 3);
                enc_px<128, 8, 12, 16, 32, 2><<<eg, 256, 0, stream>>>(
                    feat, enc_w, enc_bn_s, enc_bn_b, enc_thr, enc_beta, avg_cl, Hs, Wsz, 5);
                dim3 dg(25, B, 1);
                dec_mfma<4><<<dg, 256, 0, stream>>>(avg_cl, ap, dec_bn_s, dec_bn_b, r, 128, Hs, Wsz, 5);
            } else {
                if (split5) {
                    float* partial5 = (float*)(wsb + part5_off);
                    dim3 eg(25, B, 12);   // 4 ci-splits x 3 co-chunks
                    enc_tiled<256, 64, 16, 12, 8, true, true><<<eg, 64, 0, stream>>>(
                        feat, enc_w, enc_bn_s, enc_bn_b, enc_thr, enc_beta, nullptr, partial5, Hs, Wsz, 5);
                    int total = B * 36 * Hs * Wsz;
                    combine_lif<4, true><<<(total + 255) / 256, 256, 0, stream>>>(
                        partial5, enc_bn_s, enc_bn_b, enc_thr, enc_beta, avg_cl, Hs, Wsz, total);
                } else {
                    dim3 eg(25, B, 3);
                    enc_tiled<256, 256, 16, 12, 8, false, true><<<eg, 64, 0, stream>>>(
                        feat, enc_w, enc_bn_s, enc_bn_b, enc_thr, enc_beta, avg_cl, nullptr, Hs, Wsz, 5);
                }
                dim3 dg(9, B, 2);
                dec_mfma<4><<<dg, 256, 0, stream>>>(avg_cl, ap, dec_bn_s, dec_bn_b, r, 256, Hs, Wsz, 3);
            }
        }
    } else {
        // ================= FALLBACK (NCHW, VALU decoder) =================
        __hip_bfloat16* ws = (__hip_bfloat16*)d_ws;
        long avg_off2[3]; long eoff = 0;
        for (int l = 0; l < 3; ++l) { avg_off2[l] = eoff; eoff += (long)B * 36 * S[l] * S[l]; }
        float* partial5 = (float*)(ws + ((eoff + 7) & ~7L));
        const long part5f = 4L * B * 36 * 40 * 40;
        const size_t old_need = (size_t)((eoff + 7) & ~7L) * 2 + part5f * 4;
        const bool split5 = ws_size >= old_need;

        for (int l = 0; l < 3; ++l) {
            const int base = 9 * l;
            const float* feat     = (const float*)d_in[base + 0];
            const float* enc_w    = (const float*)d_in[base + 1];
            const float* enc_bn_s = (const float*)d_in[base + 2];
            const float* enc_bn_b = (const float*)d_in[base + 3];
            const float* enc_thr  = (const float*)d_in[base + 4];
            const float* enc_beta = (const float*)d_in[base + 5];
            const float* dec_w    = (const float*)d_in[base + 6];
            const float* dec_bn_s = (const float*)d_in[base + 7];
            const float* dec_bn_b = (const float*)d_in[base + 8];

            const int Hs = S[l], Wsz = S[l], Cl = C[l];
            __hip_bfloat16* avg = ws + avg_off2[l];
            float* r = out + out_off[l];

            if (l == 0) {
                dim3 eg(100, B, 3);
                enc_tiled<64, 64, 16, 12, 16, false, false><<<eg, 256, 0, stream>>>(
                    feat, enc_w, enc_bn_s, enc_bn_b, enc_thr, enc_beta, avg, nullptr, Hs, Wsz, 10);
                dim3 dg(100, B, 2);
                dec_tiled<32, 16><<<dg, 256, 0, stream>>>(avg, dec_w, dec_bn_s, dec_bn_b, r, Cl, Hs, Wsz, 10);
            } else if (l == 1) {
                dim3 eg(25, B, 3);
                enc_tiled<128, 128, 16, 12, 16, false, false><<<eg, 256, 0, stream>>>(
                    feat, enc_w, enc_bn_s, enc_bn_b, enc_thr, enc_beta, avg, nullptr, Hs, Wsz, 5);
                dim3 dg(25, B, 4);
                dec_tiled<32, 16><<<dg, 256, 0, stream>>>(avg, dec_w, dec_bn_s, dec_bn_b, r, Cl, Hs, Wsz, 5);
            } else {
                if (split5) {
                    dim3 eg(25, B, 12);
                    enc_tiled<256, 64, 16, 12, 8, true, false><<<eg, 64, 0, stream>>>(
                        feat, enc_w, enc_bn_s, enc_bn_b, enc_thr, enc_beta, nullptr, partial5, Hs, Wsz, 5);
                    int total = B * 36 * Hs * Wsz;
                    combine_lif<4, false><<<(total + 255) / 256, 256, 0, stream>>>(
                        partial5, enc_bn_s, enc_bn_b, enc_thr, enc_beta, avg, Hs, Wsz, total);
                } else {
                    dim3 eg(25, B, 3);
                    enc_tiled<256, 256, 16, 12, 8, false, false><<<eg, 64, 0, stream>>>(
                        feat, enc_w, enc_bn_s, enc_bn_b, enc_thr, enc_beta, avg, nullptr, Hs, Wsz, 5);
                }
                dim3 dg(25, B, 16);
                dec_tiled<16, 8><<<dg, 64, 0, stream>>>(avg, dec_w, dec_bn_s, dec_bn_b, r, Cl, Hs, Wsz, 5);
            }
        }
    }
}